// Round 1
// baseline (346.852 us; speedup 1.0000x reference)
//
#include <hip/hip_runtime.h>
#include <hip/hip_bf16.h>
#include <stdint.h>

#define BS 4
#define NS 4096
#define NT 16384
#define CS 256
#define CT 128
#define KC1 384      // CS+CT
#define NOUT 256
#define MTOT (BS*NT) // 65536

typedef __attribute__((ext_vector_type(4))) float floatx4;
typedef __attribute__((ext_vector_type(8))) short shortx8;
typedef __attribute__((ext_vector_type(8))) __bf16 bf16x8;

__device__ __forceinline__ unsigned short f2bf(float f) {
  unsigned int u = __builtin_bit_cast(unsigned int, f);
  u += 0x7FFFu + ((u >> 16) & 1u);
  return (unsigned short)(u >> 16);
}

// ---------------- weight transpose + bf16 cast ----------------
// w1t[n*384+k] = bf16(w1[k*256+n]); w2t[n*256+k] = bf16(w2[k*256+n])
__global__ __launch_bounds__(256) void wt_kernel(const float* __restrict__ w1,
    const float* __restrict__ w2, unsigned short* __restrict__ w1t,
    unsigned short* __restrict__ w2t) {
  int i = blockIdx.x * 256 + threadIdx.x;
  if (i < KC1 * NOUT) {
    int n = i / KC1, k = i - n * KC1;
    w1t[i] = f2bf(w1[k * NOUT + n]);
  }
  if (i < NOUT * NOUT) {
    int n = i >> 8, k = i & 255;
    w2t[i] = f2bf(w2[k * NOUT + n]);
  }
}

// ---------------- three_nn ----------------
#define INSERT3(dd, d0,d1,d2,i0,i1,i2, jj) \
  if (dd < d2) { \
    if (dd < d1) { d2=d1; i2=i1; \
      if (dd < d0) { d1=d0; i1=i0; d0=dd; i0=jj; } \
      else { d1=dd; i1=jj; } \
    } else { d2=dd; i2=jj; } }

// merge this lane's sorted triple with partner (xor delta); lower-sub list wins ties
__device__ __forceinline__ void pair_merge(float& d0, float& d1, float& d2,
                                           int& i0, int& i1, int& i2,
                                           int delta, int sub) {
  float e0 = __shfl_xor(d0, delta);
  float e1 = __shfl_xor(d1, delta);
  float e2 = __shfl_xor(d2, delta);
  int   y0 = __shfl_xor(i0, delta);
  int   y1 = __shfl_xor(i1, delta);
  int   y2 = __shfl_xor(i2, delta);
  float a0,a1,a2,b0,b1,b2; int x0,x1,x2,z0,z1,z2;
  if ((sub & delta) == 0) { a0=d0;a1=d1;a2=d2; x0=i0;x1=i1;x2=i2;
                            b0=e0;b1=e1;b2=e2; z0=y0;z1=y1;z2=y2; }
  else                    { a0=e0;a1=e1;a2=e2; x0=y0;x1=y1;x2=y2;
                            b0=d0;b1=d1;b2=d2; z0=i0;z1=i1;z2=i2; }
  bool t = a0 <= b0;
  d0 = t ? a0 : b0; i0 = t ? x0 : z0;
  float na0 = t ? a1 : a0; int nx0 = t ? x1 : x0;
  float na1 = t ? a2 : a1; int nx1 = t ? x2 : x1;
  float nb0 = t ? b0 : b1; int nz0 = t ? z0 : z1;
  float nb1 = t ? b1 : b2; int nz1 = t ? z1 : z2;
  t = na0 <= nb0;
  d1 = t ? na0 : nb0; i1 = t ? nx0 : nz0;
  float ma0 = t ? na1 : na0; int mx0 = t ? nx1 : nx0;
  float mb0 = t ? nb0 : nb1; int mz0 = t ? nz0 : nz1;
  t = ma0 <= mb0;
  d2 = t ? ma0 : mb0; i2 = t ? mx0 : mz0;
}

// grid: 512 blocks (128 per batch), 256 threads.
// block handles 128 targets; thread = (lt = tid>>2 in [0,64), sub = tid&3 source split)
// thread scans source range [sub*1024, sub*1024+1024) for targets lt and lt+64.
__global__ __launch_bounds__(256) void nn_kernel(const float* __restrict__ xyzt,
    const float* __restrict__ xyzs, int* __restrict__ idx_out,
    float* __restrict__ w_out) {
  __shared__ float4 s_src[NS];  // 64 KB
  int tid = threadIdx.x;
  int b = blockIdx.x >> 7;
  int tgt0 = (blockIdx.x & 127) * 128;
  const float* src = xyzs + (size_t)b * NS * 3;
  for (int p = tid; p < NS; p += 256) {
    s_src[p] = make_float4(src[3*p], src[3*p+1], src[3*p+2], 0.f);
  }
  __syncthreads();
  int lt = tid >> 2, sub = tid & 3;
  const float* tpA = xyzt + ((size_t)b * NT + tgt0 + lt) * 3;
  const float* tpB = tpA + 64 * 3;
  float txA = tpA[0], tyA = tpA[1], tzA = tpA[2];
  float txB = tpB[0], tyB = tpB[1], tzB = tpB[2];
  float d0a=1e30f,d1a=1e30f,d2a=1e30f; int i0a=0,i1a=0,i2a=0;
  float d0b=1e30f,d1b=1e30f,d2b=1e30f; int i0b=0,i1b=0,i2b=0;
  int j0 = sub << 10;
  #pragma unroll 4
  for (int c = 0; c < 1024; ++c) {
    int j = j0 + c;
    float4 s = s_src[j];
    float dx = txA - s.x, dy = tyA - s.y, dz = tzA - s.z;
    float dA = dx*dx + dy*dy + dz*dz;
    INSERT3(dA, d0a,d1a,d2a,i0a,i1a,i2a, j);
    dx = txB - s.x; dy = tyB - s.y; dz = tzB - s.z;
    float dB = dx*dx + dy*dy + dz*dz;
    INSERT3(dB, d0b,d1b,d2b,i0b,i1b,i2b, j);
  }
  // merge the 4 sub-splits (adjacent lanes) via shuffles
  pair_merge(d0a,d1a,d2a,i0a,i1a,i2a, 1, sub);
  pair_merge(d0a,d1a,d2a,i0a,i1a,i2a, 2, sub);
  pair_merge(d0b,d1b,d2b,i0b,i1b,i2b, 1, sub);
  pair_merge(d0b,d1b,d2b,i0b,i1b,i2b, 2, sub);
  if (sub == 0) {
    // target A
    {
      float r0 = fmaxf(sqrtf(d0a), 1e-10f);
      float r1 = fmaxf(sqrtf(d1a), 1e-10f);
      float r2 = fmaxf(sqrtf(d2a), 1e-10f);
      float v0 = 1.f/r0, v1 = 1.f/r1, v2 = 1.f/r2;
      float sc = 1.f / ((v0+v1+v2) * (1.f + 1e-6f));
      size_t o = ((size_t)b*NT + tgt0 + lt) * 3;
      idx_out[o]=i0a; idx_out[o+1]=i1a; idx_out[o+2]=i2a;
      w_out[o]=v0*sc; w_out[o+1]=v1*sc; w_out[o+2]=v2*sc;
    }
    // target B
    {
      float r0 = fmaxf(sqrtf(d0b), 1e-10f);
      float r1 = fmaxf(sqrtf(d1b), 1e-10f);
      float r2 = fmaxf(sqrtf(d2b), 1e-10f);
      float v0 = 1.f/r0, v1 = 1.f/r1, v2 = 1.f/r2;
      float sc = 1.f / ((v0+v1+v2) * (1.f + 1e-6f));
      size_t o = ((size_t)b*NT + tgt0 + 64 + lt) * 3;
      idx_out[o]=i0b; idx_out[o+1]=i1b; idx_out[o+2]=i2b;
      w_out[o]=v0*sc; w_out[o+1]=v1*sc; w_out[o+2]=v2*sc;
    }
  }
}

// ---------------- build X = [interp | feats_target] in bf16 ----------------
// grid: MTOT/4 blocks, 256 threads; 4 rows/block, 64 lanes per row.
__global__ __launch_bounds__(256) void build_x(const float* __restrict__ ft,
    const float* __restrict__ fs, const int* __restrict__ idxb,
    const float* __restrict__ wgtb, unsigned short* __restrict__ X) {
  int row = blockIdx.x * 4 + (threadIdx.x >> 6);
  int lane = threadIdx.x & 63;
  int b = row >> 14;
  int t = row & (NT - 1);
  const int* ip = idxb + (size_t)row * 3;
  const float* wp = wgtb + (size_t)row * 3;
  int i0 = ip[0], i1 = ip[1], i2 = ip[2];
  float w0 = wp[0], w1 = wp[1], w2 = wp[2];
  const float* fsb = fs + (size_t)b * NS * CS;
  float4 a = *((const float4*)(fsb + (size_t)i0 * CS) + lane);
  float4 c = *((const float4*)(fsb + (size_t)i1 * CS) + lane);
  float4 e = *((const float4*)(fsb + (size_t)i2 * CS) + lane);
  float4 v;
  v.x = w0*a.x + w1*c.x + w2*e.x;
  v.y = w0*a.y + w1*c.y + w2*e.y;
  v.z = w0*a.z + w1*c.z + w2*e.z;
  v.w = w0*a.w + w1*c.w + w2*e.w;
  unsigned short* xr = X + (size_t)row * KC1;
  ushort4 pk; pk.x = f2bf(v.x); pk.y = f2bf(v.y); pk.z = f2bf(v.z); pk.w = f2bf(v.w);
  *(ushort4*)(xr + lane*4) = pk;
  float2 tv = *((const float2*)(ft + ((size_t)b*NT + t)*CT) + lane);
  ushort2 pk2; pk2.x = f2bf(tv.x); pk2.y = f2bf(tv.y);
  *(ushort2*)(xr + CS + lane*2) = pk2;
}

// ---------------- GEMM: C = relu(A @ Bt^T), A[M x K] bf16, Bt[256 x K] bf16 ----------------
// BM=128, BN=128, BK=64; 256 threads = 4 waves, each 64x64 (4x4 frags of 16x16x32)
template<int K, bool OUT_BF16>
__global__ __launch_bounds__(256) void mlp_gemm(const unsigned short* __restrict__ A,
    const unsigned short* __restrict__ Bt, void* __restrict__ Cout) {
  constexpr int LDT = 72;  // padded bf16 stride (144 B: 2-way bank alias only)
  __shared__ __attribute__((aligned(16))) short sA[128 * LDT];
  __shared__ __attribute__((aligned(16))) short sB[128 * LDT];
  int tid = threadIdx.x;
  int m0 = blockIdx.x * 128;
  int n0 = blockIdx.y * 128;
  int wave = tid >> 6, lane = tid & 63;
  int wm = (wave >> 1) * 64, wn = (wave & 1) * 64;
  int fr = lane & 15, quad = lane >> 4;
  floatx4 zero = {0.f, 0.f, 0.f, 0.f};
  floatx4 acc[4][4];
  #pragma unroll
  for (int i = 0; i < 4; ++i)
    #pragma unroll
    for (int j = 0; j < 4; ++j) acc[i][j] = zero;

  for (int kt = 0; kt < K; kt += 64) {
    #pragma unroll
    for (int i = 0; i < 4; ++i) {
      int chunk = tid + 256 * i;       // 1024 chunks of 16B
      int r = chunk >> 3, kc = chunk & 7;
      *(shortx8*)&sA[r * LDT + kc * 8] =
          *(const shortx8*)(A + (size_t)(m0 + r) * K + kt + kc * 8);
      *(shortx8*)&sB[r * LDT + kc * 8] =
          *(const shortx8*)(Bt + (size_t)(n0 + r) * K + kt + kc * 8);
    }
    __syncthreads();
    #pragma unroll
    for (int kk = 0; kk < 64; kk += 32) {
      bf16x8 af[4], bfr[4];
      #pragma unroll
      for (int mi = 0; mi < 4; ++mi)
        af[mi] = __builtin_bit_cast(bf16x8,
            *(const shortx8*)&sA[(wm + mi*16 + fr)*LDT + kk + quad*8]);
      #pragma unroll
      for (int ni = 0; ni < 4; ++ni)
        bfr[ni] = __builtin_bit_cast(bf16x8,
            *(const shortx8*)&sB[(wn + ni*16 + fr)*LDT + kk + quad*8]);
      #pragma unroll
      for (int mi = 0; mi < 4; ++mi)
        #pragma unroll
        for (int ni = 0; ni < 4; ++ni)
          acc[mi][ni] = __builtin_amdgcn_mfma_f32_16x16x32_bf16(
              af[mi], bfr[ni], acc[mi][ni], 0, 0, 0);
    }
    __syncthreads();
  }
  // epilogue: C/D layout col=lane&15, row=quad*4+reg
  #pragma unroll
  for (int mi = 0; mi < 4; ++mi) {
    #pragma unroll
    for (int ni = 0; ni < 4; ++ni) {
      #pragma unroll
      for (int r = 0; r < 4; ++r) {
        int grow = m0 + wm + mi*16 + quad*4 + r;
        int gcol = n0 + wn + ni*16 + fr;
        float v = fmaxf(acc[mi][ni][r], 0.f);
        if constexpr (OUT_BF16)
          ((unsigned short*)Cout)[(size_t)grow * NOUT + gcol] = f2bf(v);
        else
          ((float*)Cout)[(size_t)grow * NOUT + gcol] = v;
      }
    }
  }
}

extern "C" void kernel_launch(void* const* d_in, const int* in_sizes, int n_in,
                              void* d_out, int out_size, void* d_ws, size_t ws_size,
                              hipStream_t stream) {
  (void)in_sizes; (void)n_in; (void)out_size; (void)ws_size;
  const float* xyzt = (const float*)d_in[0];
  const float* xyzs = (const float*)d_in[1];
  const float* ft   = (const float*)d_in[2];
  const float* fs   = (const float*)d_in[3];
  const float* w1   = (const float*)d_in[4];
  const float* w2   = (const float*)d_in[5];

  char* p = (char*)d_ws;
  unsigned short* w1t = (unsigned short*)p; p += (size_t)KC1*NOUT*2;   // 192 KB
  unsigned short* w2t = (unsigned short*)p; p += (size_t)NOUT*NOUT*2;  // 128 KB
  int*   idxb = (int*)p;   p += (size_t)MTOT*3*4;                      // 768 KB
  float* wgtb = (float*)p; p += (size_t)MTOT*3*4;                      // 768 KB
  unsigned short* Xb = (unsigned short*)p; p += (size_t)MTOT*KC1*2;    // 48 MB
  unsigned short* Y1 = (unsigned short*)p; p += (size_t)MTOT*NOUT*2;   // 32 MB

  hipLaunchKernelGGL(wt_kernel, dim3(384), dim3(256), 0, stream, w1, w2, w1t, w2t);
  hipLaunchKernelGGL(nn_kernel, dim3(512), dim3(256), 0, stream, xyzt, xyzs, idxb, wgtb);
  hipLaunchKernelGGL(build_x, dim3(MTOT/4), dim3(256), 0, stream, ft, fs, idxb, wgtb, Xb);
  hipLaunchKernelGGL((mlp_gemm<KC1, true>),  dim3(MTOT/128, 2), dim3(256), 0, stream, Xb, w1t, (void*)Y1);
  hipLaunchKernelGGL((mlp_gemm<NOUT, false>), dim3(MTOT/128, 2), dim3(256), 0, stream, Y1, w2t, d_out);
}

// Round 3
// 344.120 us; speedup vs baseline: 1.0079x; 1.0079x over previous
//
#include <hip/hip_runtime.h>
#include <hip/hip_bf16.h>
#include <stdint.h>

#define BS 4
#define NS 4096
#define NT 16384
#define CS 256
#define CT 128
#define KC1 384      // CS+CT
#define NOUT 256
#define MTOT (BS*NT) // 65536

typedef __attribute__((ext_vector_type(4))) float floatx4;
typedef __attribute__((ext_vector_type(8))) short shortx8;
typedef __attribute__((ext_vector_type(8))) __bf16 bf16x8;

__device__ __forceinline__ unsigned short f2bf(float f) {
  unsigned int u = __builtin_bit_cast(unsigned int, f);
  u += 0x7FFFu + ((u >> 16) & 1u);
  return (unsigned short)(u >> 16);
}

// ---------------- weight transpose + bf16 cast ----------------
__global__ __launch_bounds__(256) void wt_kernel(const float* __restrict__ w1,
    const float* __restrict__ w2, unsigned short* __restrict__ w1t,
    unsigned short* __restrict__ w2t) {
  int i = blockIdx.x * 256 + threadIdx.x;
  if (i < KC1 * NOUT) {
    int n = i / KC1, k = i - n * KC1;
    w1t[i] = f2bf(w1[k * NOUT + n]);
  }
  if (i < NOUT * NOUT) {
    int n = i >> 8, k = i & 255;
    w2t[i] = f2bf(w2[k * NOUT + n]);
  }
}

// ---------------- three_nn ----------------
// branchless sorted-insert of (sc,jj) into (d0<=d1<=d2)
__device__ __forceinline__ void ins3(float sc, int jj,
    float& d0, float& d1, float& d2, int& i0, int& i1, int& i2) {
  bool l0 = sc < d0, l1 = sc < d1, l2 = sc < d2;
  d2 = l1 ? d1 : (l2 ? sc : d2);
  i2 = l1 ? i1 : (l2 ? jj : i2);
  d1 = l0 ? d0 : (l1 ? sc : d1);
  i1 = l0 ? i0 : (l1 ? jj : i1);
  d0 = l0 ? sc : d0;
  i0 = l0 ? jj : i0;
}

// merge this lane's sorted triple with partner (xor delta); lower-sub list wins ties
__device__ __forceinline__ void pair_merge(float& d0, float& d1, float& d2,
                                           int& i0, int& i1, int& i2,
                                           int delta, int sub) {
  float e0 = __shfl_xor(d0, delta);
  float e1 = __shfl_xor(d1, delta);
  float e2 = __shfl_xor(d2, delta);
  int   y0 = __shfl_xor(i0, delta);
  int   y1 = __shfl_xor(i1, delta);
  int   y2 = __shfl_xor(i2, delta);
  float a0,a1,a2,b0,b1,b2; int x0,x1,x2,z0,z1,z2;
  if ((sub & delta) == 0) { a0=d0;a1=d1;a2=d2; x0=i0;x1=i1;x2=i2;
                            b0=e0;b1=e1;b2=e2; z0=y0;z1=y1;z2=y2; }
  else                    { a0=e0;a1=e1;a2=e2; x0=y0;x1=y1;x2=y2;
                            b0=d0;b1=d1;b2=d2; z0=i0;z1=i1;z2=i2; }
  bool t = a0 <= b0;
  d0 = t ? a0 : b0; i0 = t ? x0 : z0;
  float na0 = t ? a1 : a0; int nx0 = t ? x1 : x0;
  float na1 = t ? a2 : a1; int nx1 = t ? x2 : x1;
  float nb0 = t ? b0 : b1; int nz0 = t ? z0 : z1;
  float nb1 = t ? b1 : b2; int nz1 = t ? z1 : z2;
  t = na0 <= nb0;
  d1 = t ? na0 : nb0; i1 = t ? nx0 : nz0;
  float ma0 = t ? na1 : na0; int mx0 = t ? nx1 : nx0;
  float mb0 = t ? nb0 : nb1; int mz0 = t ? nz0 : nz1;
  t = ma0 <= mb0;
  d2 = t ? ma0 : mb0; i2 = t ? mx0 : mz0;
}

// grid: 512 blocks (128 per batch), 256 threads.
// thread = (tgrp = tid>>3 -> 4 targets tgt0+tgrp*4+{0..3}, sub = tid&7).
// thread scans sources p = 8c + sub, c in [0,512): wave reads 8 consecutive
// float4s per ds_read (bank-conflict-free, 8-way broadcast over tgrps).
// Exact d^2 = dx^2+dy^2+dz^2 (no cancellation), fully branchless insert.
__global__ __launch_bounds__(256) void nn_kernel(const float* __restrict__ xyzt,
    const float* __restrict__ xyzs, int* __restrict__ idx_out,
    float* __restrict__ w_out) {
  __shared__ float4 s_src[NS];  // 64 KB: (x,y,z,0)
  int tid = threadIdx.x;
  int b = blockIdx.x >> 7;
  int tgt0 = (blockIdx.x & 127) * 128;
  const float* src = xyzs + (size_t)b * NS * 3;
  for (int p = tid; p < NS; p += 256) {
    s_src[p] = make_float4(src[3*p], src[3*p+1], src[3*p+2], 0.f);
  }
  __syncthreads();
  int tgrp = tid >> 3, sub = tid & 7;
  int tBase = tgt0 + tgrp * 4;
  // load 4 targets' coords via 3 float4 loads (48-byte aligned)
  const float4* tp = (const float4*)(xyzt + ((size_t)b * NT + tBase) * 3);
  float4 f0 = tp[0], f1 = tp[1], f2 = tp[2];
  float tx[4], ty[4], tz[4];
  tx[0]=f0.x; ty[0]=f0.y; tz[0]=f0.z;
  tx[1]=f0.w; ty[1]=f1.x; tz[1]=f1.y;
  tx[2]=f1.z; ty[2]=f1.w; tz[2]=f2.x;
  tx[3]=f2.y; ty[3]=f2.z; tz[3]=f2.w;
  float d0[4], d1[4], d2[4];
  int i0[4], i1[4], i2[4];
  #pragma unroll
  for (int t = 0; t < 4; ++t) {
    d0[t]=1e30f; d1[t]=1e30f; d2[t]=1e30f; i0[t]=0; i1[t]=0; i2[t]=0;
  }
  const float4* sp = s_src + sub;  // p = 8c + sub
  #pragma unroll 4
  for (int c = 0; c < 512; ++c) {
    float4 s = sp[c << 3];
    int j = (c << 3) + sub;
    #pragma unroll
    for (int t = 0; t < 4; ++t) {
      float dx = tx[t] - s.x, dy = ty[t] - s.y, dz = tz[t] - s.z;
      float q = dx*dx + dy*dy + dz*dz;
      ins3(q, j, d0[t], d1[t], d2[t], i0[t], i1[t], i2[t]);
    }
  }
  // merge the 8 sub-streams (xor 1,2,4 within each 8-lane group)
  #pragma unroll
  for (int t = 0; t < 4; ++t) {
    pair_merge(d0[t],d1[t],d2[t],i0[t],i1[t],i2[t], 1, sub);
    pair_merge(d0[t],d1[t],d2[t],i0[t],i1[t],i2[t], 2, sub);
    pair_merge(d0[t],d1[t],d2[t],i0[t],i1[t],i2[t], 4, sub);
  }
  if (sub == 0) {
    #pragma unroll
    for (int t = 0; t < 4; ++t) {
      float r0 = fmaxf(sqrtf(d0[t]), 1e-10f);
      float r1 = fmaxf(sqrtf(d1[t]), 1e-10f);
      float r2 = fmaxf(sqrtf(d2[t]), 1e-10f);
      float v0 = 1.f/r0, v1 = 1.f/r1, v2 = 1.f/r2;
      float sc = 1.f / ((v0 + v1 + v2) * (1.f + 1e-6f));
      size_t o = ((size_t)b*NT + tBase + t) * 3;
      idx_out[o] = i0[t]; idx_out[o+1] = i1[t]; idx_out[o+2] = i2[t];
      w_out[o] = v0*sc; w_out[o+1] = v1*sc; w_out[o+2] = v2*sc;
    }
  }
}

// ---------------- build X = [interp | feats_target] in bf16 ----------------
__global__ __launch_bounds__(256) void build_x(const float* __restrict__ ft,
    const float* __restrict__ fs, const int* __restrict__ idxb,
    const float* __restrict__ wgtb, unsigned short* __restrict__ X) {
  int row = blockIdx.x * 4 + (threadIdx.x >> 6);
  int lane = threadIdx.x & 63;
  int b = row >> 14;
  int t = row & (NT - 1);
  const int* ip = idxb + (size_t)row * 3;
  const float* wp = wgtb + (size_t)row * 3;
  int i0 = ip[0], i1 = ip[1], i2 = ip[2];
  float w0 = wp[0], w1 = wp[1], w2 = wp[2];
  const float* fsb = fs + (size_t)b * NS * CS;
  float4 a = *((const float4*)(fsb + (size_t)i0 * CS) + lane);
  float4 c = *((const float4*)(fsb + (size_t)i1 * CS) + lane);
  float4 e = *((const float4*)(fsb + (size_t)i2 * CS) + lane);
  float4 v;
  v.x = w0*a.x + w1*c.x + w2*e.x;
  v.y = w0*a.y + w1*c.y + w2*e.y;
  v.z = w0*a.z + w1*c.z + w2*e.z;
  v.w = w0*a.w + w1*c.w + w2*e.w;
  unsigned short* xr = X + (size_t)row * KC1;
  ushort4 pk; pk.x = f2bf(v.x); pk.y = f2bf(v.y); pk.z = f2bf(v.z); pk.w = f2bf(v.w);
  *(ushort4*)(xr + lane*4) = pk;
  float2 tv = *((const float2*)(ft + ((size_t)b*NT + t)*CT) + lane);
  ushort2 pk2; pk2.x = f2bf(tv.x); pk2.y = f2bf(tv.y);
  *(ushort2*)(xr + CS + lane*2) = pk2;
}

// ---------------- GEMM: C = relu(A @ Bt^T), A[M x K] bf16, Bt[256 x K] bf16 ----------------
template<int K, bool OUT_BF16>
__global__ __launch_bounds__(256) void mlp_gemm(const unsigned short* __restrict__ A,
    const unsigned short* __restrict__ Bt, void* __restrict__ Cout) {
  constexpr int LDT = 72;  // padded bf16 stride
  __shared__ __attribute__((aligned(16))) short sA[128 * LDT];
  __shared__ __attribute__((aligned(16))) short sB[128 * LDT];
  int tid = threadIdx.x;
  int m0 = blockIdx.x * 128;
  int n0 = blockIdx.y * 128;
  int wave = tid >> 6, lane = tid & 63;
  int wm = (wave >> 1) * 64, wn = (wave & 1) * 64;
  int fr = lane & 15, quad = lane >> 4;
  floatx4 zero = {0.f, 0.f, 0.f, 0.f};
  floatx4 acc[4][4];
  #pragma unroll
  for (int i = 0; i < 4; ++i)
    #pragma unroll
    for (int j = 0; j < 4; ++j) acc[i][j] = zero;

  for (int kt = 0; kt < K; kt += 64) {
    #pragma unroll
    for (int i = 0; i < 4; ++i) {
      int chunk = tid + 256 * i;
      int r = chunk >> 3, kc = chunk & 7;
      *(shortx8*)&sA[r * LDT + kc * 8] =
          *(const shortx8*)(A + (size_t)(m0 + r) * K + kt + kc * 8);
      *(shortx8*)&sB[r * LDT + kc * 8] =
          *(const shortx8*)(Bt + (size_t)(n0 + r) * K + kt + kc * 8);
    }
    __syncthreads();
    #pragma unroll
    for (int kk = 0; kk < 64; kk += 32) {
      bf16x8 af[4], bfr[4];
      #pragma unroll
      for (int mi = 0; mi < 4; ++mi)
        af[mi] = __builtin_bit_cast(bf16x8,
            *(const shortx8*)&sA[(wm + mi*16 + fr)*LDT + kk + quad*8]);
      #pragma unroll
      for (int ni = 0; ni < 4; ++ni)
        bfr[ni] = __builtin_bit_cast(bf16x8,
            *(const shortx8*)&sB[(wn + ni*16 + fr)*LDT + kk + quad*8]);
      #pragma unroll
      for (int mi = 0; mi < 4; ++mi)
        #pragma unroll
        for (int ni = 0; ni < 4; ++ni)
          acc[mi][ni] = __builtin_amdgcn_mfma_f32_16x16x32_bf16(
              af[mi], bfr[ni], acc[mi][ni], 0, 0, 0);
    }
    __syncthreads();
  }
  #pragma unroll
  for (int mi = 0; mi < 4; ++mi) {
    #pragma unroll
    for (int ni = 0; ni < 4; ++ni) {
      #pragma unroll
      for (int r = 0; r < 4; ++r) {
        int grow = m0 + wm + mi*16 + quad*4 + r;
        int gcol = n0 + wn + ni*16 + fr;
        float v = fmaxf(acc[mi][ni][r], 0.f);
        if constexpr (OUT_BF16)
          ((unsigned short*)Cout)[(size_t)grow * NOUT + gcol] = f2bf(v);
        else
          ((float*)Cout)[(size_t)grow * NOUT + gcol] = v;
      }
    }
  }
}

extern "C" void kernel_launch(void* const* d_in, const int* in_sizes, int n_in,
                              void* d_out, int out_size, void* d_ws, size_t ws_size,
                              hipStream_t stream) {
  (void)in_sizes; (void)n_in; (void)out_size; (void)ws_size;
  const float* xyzt = (const float*)d_in[0];
  const float* xyzs = (const float*)d_in[1];
  const float* ft   = (const float*)d_in[2];
  const float* fs   = (const float*)d_in[3];
  const float* w1   = (const float*)d_in[4];
  const float* w2   = (const float*)d_in[5];

  char* p = (char*)d_ws;
  unsigned short* w1t = (unsigned short*)p; p += (size_t)KC1*NOUT*2;
  unsigned short* w2t = (unsigned short*)p; p += (size_t)NOUT*NOUT*2;
  int*   idxb = (int*)p;   p += (size_t)MTOT*3*4;
  float* wgtb = (float*)p; p += (size_t)MTOT*3*4;
  unsigned short* Xb = (unsigned short*)p; p += (size_t)MTOT*KC1*2;
  unsigned short* Y1 = (unsigned short*)p; p += (size_t)MTOT*NOUT*2;

  hipLaunchKernelGGL(wt_kernel, dim3(384), dim3(256), 0, stream, w1, w2, w1t, w2t);
  hipLaunchKernelGGL(nn_kernel, dim3(512), dim3(256), 0, stream, xyzt, xyzs, idxb, wgtb);
  hipLaunchKernelGGL(build_x, dim3(MTOT/4), dim3(256), 0, stream, ft, fs, idxb, wgtb, Xb);
  hipLaunchKernelGGL((mlp_gemm<KC1, true>),  dim3(MTOT/128, 2), dim3(256), 0, stream, Xb, w1t, (void*)Y1);
  hipLaunchKernelGGL((mlp_gemm<NOUT, false>), dim3(MTOT/128, 2), dim3(256), 0, stream, Y1, w2t, d_out);
}

// Round 4
// 228.353 us; speedup vs baseline: 1.5189x; 1.5070x over previous
//
#include <hip/hip_runtime.h>
#include <hip/hip_bf16.h>
#include <stdint.h>

#define BS 4
#define NS 4096
#define NT 16384
#define CS 256
#define CT 128
#define KC1 384      // CS+CT
#define NOUT 256
#define MTOT (BS*NT) // 65536
#define GR 8         // grid resolution per axis
#define NC (GR*GR*GR) // 512 cells
#define HCELL 0.125f

typedef __attribute__((ext_vector_type(4))) float floatx4;
typedef __attribute__((ext_vector_type(8))) short shortx8;
typedef __attribute__((ext_vector_type(8))) __bf16 bf16x8;

__device__ __forceinline__ unsigned short f2bf(float f) {
  unsigned int u = __builtin_bit_cast(unsigned int, f);
  u += 0x7FFFu + ((u >> 16) & 1u);
  return (unsigned short)(u >> 16);
}

__device__ __forceinline__ int cell_of(float x) {
  int c = (int)(x * 8.0f);
  return min(7, max(0, c));
}

// ---------------- weight transpose + bf16 cast ----------------
__global__ __launch_bounds__(256) void wt_kernel(const float* __restrict__ w1,
    const float* __restrict__ w2, unsigned short* __restrict__ w1t,
    unsigned short* __restrict__ w2t) {
  int i = blockIdx.x * 256 + threadIdx.x;
  if (i < KC1 * NOUT) {
    int n = i / KC1, k = i - n * KC1;
    w1t[i] = f2bf(w1[k * NOUT + n]);
  }
  if (i < NOUT * NOUT) {
    int n = i >> 8, k = i & 255;
    w2t[i] = f2bf(w2[k * NOUT + n]);
  }
}

// ---------------- bucket sources: counting sort by cell ----------------
// one block per batch, 512 threads, 8 sources each
__global__ __launch_bounds__(512) void bucket_src(const float* __restrict__ xyzs,
    float4* __restrict__ bsrc, int* __restrict__ soff) {
  __shared__ int cnt[NC];
  __shared__ int scan[NC];
  int tid = threadIdx.x;
  int b = blockIdx.x;
  const float* src = xyzs + (size_t)b * NS * 3;
  cnt[tid] = 0;
  __syncthreads();
  #pragma unroll
  for (int k = 0; k < 8; ++k) {
    int p = k * 512 + tid;
    float x = src[3*p], y = src[3*p+1], z = src[3*p+2];
    int c = (cell_of(z) * GR + cell_of(y)) * GR + cell_of(x);
    atomicAdd(&cnt[c], 1);
  }
  __syncthreads();
  scan[tid] = cnt[tid];
  __syncthreads();
  for (int off = 1; off < NC; off <<= 1) {
    int v = (tid >= off) ? scan[tid - off] : 0;
    __syncthreads();
    scan[tid] += v;
    __syncthreads();
  }
  // exclusive offset; reuse cnt as scatter cursor
  int excl = scan[tid] - cnt[tid];
  cnt[tid] = excl;
  soff[b * (NC + 1) + tid] = excl;
  if (tid == 0) soff[b * (NC + 1) + NC] = NS;
  __syncthreads();
  #pragma unroll
  for (int k = 0; k < 8; ++k) {
    int p = k * 512 + tid;
    float x = src[3*p], y = src[3*p+1], z = src[3*p+2];
    int c = (cell_of(z) * GR + cell_of(y)) * GR + cell_of(x);
    int slot = atomicAdd(&cnt[c], 1);
    bsrc[(size_t)b * NS + slot] = make_float4(x, y, z, __int_as_float(p));
  }
}

// ---------------- sort targets by cell ----------------
// one block per batch, 1024 threads, 16 targets each
__global__ __launch_bounds__(1024) void sort_tgt(const float* __restrict__ xyzt,
    float4* __restrict__ stgt) {
  __shared__ int cnt[NC];
  __shared__ int scan[NC];
  int tid = threadIdx.x;
  int b = blockIdx.x;
  const float* tp = xyzt + (size_t)b * NT * 3;
  if (tid < NC) cnt[tid] = 0;
  __syncthreads();
  #pragma unroll
  for (int k = 0; k < 16; ++k) {
    int p = k * 1024 + tid;
    float x = tp[3*p], y = tp[3*p+1], z = tp[3*p+2];
    int c = (cell_of(z) * GR + cell_of(y)) * GR + cell_of(x);
    atomicAdd(&cnt[c], 1);
  }
  __syncthreads();
  if (tid < NC) scan[tid] = cnt[tid];
  __syncthreads();
  for (int off = 1; off < NC; off <<= 1) {
    int v = (tid < NC && tid >= off) ? scan[tid - off] : 0;
    __syncthreads();
    if (tid < NC) scan[tid] += v;
    __syncthreads();
  }
  if (tid < NC) cnt[tid] = scan[tid] - cnt[tid];  // exclusive, reused as cursor
  __syncthreads();
  #pragma unroll
  for (int k = 0; k < 16; ++k) {
    int p = k * 1024 + tid;
    float x = tp[3*p], y = tp[3*p+1], z = tp[3*p+2];
    int c = (cell_of(z) * GR + cell_of(y)) * GR + cell_of(x);
    int slot = atomicAdd(&cnt[c], 1);
    stgt[(size_t)b * NT + slot] = make_float4(x, y, z, __int_as_float(p));
  }
}

// ---------------- three_nn (bucketed) ----------------
// branchless sorted-insert of (sc,jj) into (d0<=d1<=d2)
__device__ __forceinline__ void ins3(float sc, int jj,
    float& d0, float& d1, float& d2, int& i0, int& i1, int& i2) {
  bool l0 = sc < d0, l1 = sc < d1, l2 = sc < d2;
  d2 = l1 ? d1 : (l2 ? sc : d2);
  i2 = l1 ? i1 : (l2 ? jj : i2);
  d1 = l0 ? d0 : (l1 ? sc : d1);
  i1 = l0 ? i0 : (l1 ? jj : i1);
  d0 = l0 ? sc : d0;
  i0 = l0 ? jj : i0;
}

__device__ __forceinline__ void pair_merge(float& d0, float& d1, float& d2,
                                           int& i0, int& i1, int& i2,
                                           int delta, int sub) {
  float e0 = __shfl_xor(d0, delta);
  float e1 = __shfl_xor(d1, delta);
  float e2 = __shfl_xor(d2, delta);
  int   y0 = __shfl_xor(i0, delta);
  int   y1 = __shfl_xor(i1, delta);
  int   y2 = __shfl_xor(i2, delta);
  float a0,a1,a2,b0,b1,b2; int x0,x1,x2,z0,z1,z2;
  if ((sub & delta) == 0) { a0=d0;a1=d1;a2=d2; x0=i0;x1=i1;x2=i2;
                            b0=e0;b1=e1;b2=e2; z0=y0;z1=y1;z2=y2; }
  else                    { a0=e0;a1=e1;a2=e2; x0=y0;x1=y1;x2=y2;
                            b0=d0;b1=d1;b2=d2; z0=i0;z1=i1;z2=i2; }
  bool t = a0 <= b0;
  d0 = t ? a0 : b0; i0 = t ? x0 : z0;
  float na0 = t ? a1 : a0; int nx0 = t ? x1 : x0;
  float na1 = t ? a2 : a1; int nx1 = t ? x2 : x1;
  float nb0 = t ? b0 : b1; int nz0 = t ? z0 : z1;
  float nb1 = t ? b1 : b2; int nz1 = t ? z1 : z2;
  t = na0 <= nb0;
  d1 = t ? na0 : nb0; i1 = t ? nx0 : nz0;
  float ma0 = t ? na1 : na0; int mx0 = t ? nx1 : nx0;
  float mb0 = t ? nb0 : nb1; int mz0 = t ? nz0 : nz1;
  t = ma0 <= mb0;
  d2 = t ? ma0 : mb0; i2 = t ? mx0 : mz0;
}

// grid: 512 blocks (128 per batch), 256 threads.
// block handles 128 sorted targets; thread-pair (tpair=tid>>1) per target,
// half=tid&1 splits the 9 window rows (3 x-adjacent cells = 1 contiguous range).
// Exact d^2; clearance-guarded fallback full scan (practically never fires).
__global__ __launch_bounds__(256) void nn_kernel(const float4* __restrict__ stgt,
    const float4* __restrict__ bsrc, const int* __restrict__ soff,
    int* __restrict__ idx_out, float* __restrict__ w_out) {
  __shared__ float4 s_src[NS];   // 64 KB
  __shared__ int s_off[NC + 1];  // 2052 B
  int tid = threadIdx.x;
  int b = blockIdx.x >> 7;
  int tseg = blockIdx.x & 127;
  for (int i = tid; i < NS; i += 256) s_src[i] = bsrc[(size_t)b * NS + i];
  for (int i = tid; i < NC + 1; i += 256) s_off[i] = soff[b * (NC + 1) + i];
  __syncthreads();
  int tpair = tid >> 1, half = tid & 1;
  float4 tg = stgt[(size_t)b * NT + tseg * 128 + tpair];
  float tx = tg.x, ty = tg.y, tz = tg.z;
  int orig = __float_as_int(tg.w);
  int cx = cell_of(tx), cy = cell_of(ty), cz = cell_of(tz);
  int wx = min(max(cx, 1), 6) - 1;
  int wy = min(max(cy, 1), 6) - 1;
  int wz = min(max(cz, 1), 6) - 1;
  float d0 = 1e30f, d1 = 1e30f, d2 = 1e30f;
  int i0 = 0, i1 = 0, i2 = 0;
  // 9 rows (ez,ey); each row = 3 x-adjacent cells = contiguous source range
  for (int r = half; r < 9; r += 2) {
    int ez = wz + r / 3, ey = wy + r % 3;
    int rowc = (ez * GR + ey) * GR + wx;
    int lo = s_off[rowc], hi = s_off[rowc + 3];
    for (int p = lo; p < hi; ++p) {
      float4 s = s_src[p];
      float dx = tx - s.x, dy = ty - s.y, dz = tz - s.z;
      float q = dx*dx + dy*dy + dz*dz;
      ins3(q, __float_as_int(s.w), d0, d1, d2, i0, i1, i2);
    }
  }
  pair_merge(d0, d1, d2, i0, i1, i2, 1, half);
  // exactness guard: unscanned cells are >= clearance away
  float clx = fminf(wx > 0 ? tx - wx * HCELL : 1e30f,
                    wx + 3 < GR ? (wx + 3) * HCELL - tx : 1e30f);
  float cly = fminf(wy > 0 ? ty - wy * HCELL : 1e30f,
                    wy + 3 < GR ? (wy + 3) * HCELL - ty : 1e30f);
  float clz = fminf(wz > 0 ? tz - wz * HCELL : 1e30f,
                    wz + 3 < GR ? (wz + 3) * HCELL - tz : 1e30f);
  float cl = fminf(clx, fminf(cly, clz));
  bool bad = d2 > cl * cl;
  if (__any(bad)) {
    if (bad) {
      d0 = d1 = d2 = 1e30f; i0 = i1 = i2 = 0;
      for (int p = half; p < NS; p += 2) {
        float4 s = s_src[p];
        float dx = tx - s.x, dy = ty - s.y, dz = tz - s.z;
        float q = dx*dx + dy*dy + dz*dz;
        ins3(q, __float_as_int(s.w), d0, d1, d2, i0, i1, i2);
      }
    }
    pair_merge(d0, d1, d2, i0, i1, i2, 1, half);
  }
  if (half == 0) {
    float r0 = fmaxf(sqrtf(d0), 1e-10f);
    float r1 = fmaxf(sqrtf(d1), 1e-10f);
    float r2 = fmaxf(sqrtf(d2), 1e-10f);
    float v0 = 1.f/r0, v1 = 1.f/r1, v2 = 1.f/r2;
    float sc = 1.f / ((v0 + v1 + v2) * (1.f + 1e-6f));
    size_t o = ((size_t)b * NT + orig) * 3;
    idx_out[o] = i0; idx_out[o+1] = i1; idx_out[o+2] = i2;
    w_out[o] = v0*sc; w_out[o+1] = v1*sc; w_out[o+2] = v2*sc;
  }
}

// ---------------- build X = [interp | feats_target] in bf16 ----------------
__global__ __launch_bounds__(256) void build_x(const float* __restrict__ ft,
    const float* __restrict__ fs, const int* __restrict__ idxb,
    const float* __restrict__ wgtb, unsigned short* __restrict__ X) {
  int row = blockIdx.x * 4 + (threadIdx.x >> 6);
  int lane = threadIdx.x & 63;
  int b = row >> 14;
  int t = row & (NT - 1);
  const int* ip = idxb + (size_t)row * 3;
  const float* wp = wgtb + (size_t)row * 3;
  int i0 = ip[0], i1 = ip[1], i2 = ip[2];
  float w0 = wp[0], w1 = wp[1], w2 = wp[2];
  const float* fsb = fs + (size_t)b * NS * CS;
  float4 a = *((const float4*)(fsb + (size_t)i0 * CS) + lane);
  float4 c = *((const float4*)(fsb + (size_t)i1 * CS) + lane);
  float4 e = *((const float4*)(fsb + (size_t)i2 * CS) + lane);
  float4 v;
  v.x = w0*a.x + w1*c.x + w2*e.x;
  v.y = w0*a.y + w1*c.y + w2*e.y;
  v.z = w0*a.z + w1*c.z + w2*e.z;
  v.w = w0*a.w + w1*c.w + w2*e.w;
  unsigned short* xr = X + (size_t)row * KC1;
  ushort4 pk; pk.x = f2bf(v.x); pk.y = f2bf(v.y); pk.z = f2bf(v.z); pk.w = f2bf(v.w);
  *(ushort4*)(xr + lane*4) = pk;
  float2 tv = *((const float2*)(ft + ((size_t)b*NT + t)*CT) + lane);
  ushort2 pk2; pk2.x = f2bf(tv.x); pk2.y = f2bf(tv.y);
  *(ushort2*)(xr + CS + lane*2) = pk2;
}

// ---------------- GEMM: C = relu(A @ Bt^T), A[M x K] bf16, Bt[256 x K] bf16 ----------------
template<int K, bool OUT_BF16>
__global__ __launch_bounds__(256) void mlp_gemm(const unsigned short* __restrict__ A,
    const unsigned short* __restrict__ Bt, void* __restrict__ Cout) {
  constexpr int LDT = 72;  // padded bf16 stride
  __shared__ __attribute__((aligned(16))) short sA[128 * LDT];
  __shared__ __attribute__((aligned(16))) short sB[128 * LDT];
  int tid = threadIdx.x;
  int m0 = blockIdx.x * 128;
  int n0 = blockIdx.y * 128;
  int wave = tid >> 6, lane = tid & 63;
  int wm = (wave >> 1) * 64, wn = (wave & 1) * 64;
  int fr = lane & 15, quad = lane >> 4;
  floatx4 zero = {0.f, 0.f, 0.f, 0.f};
  floatx4 acc[4][4];
  #pragma unroll
  for (int i = 0; i < 4; ++i)
    #pragma unroll
    for (int j = 0; j < 4; ++j) acc[i][j] = zero;

  for (int kt = 0; kt < K; kt += 64) {
    #pragma unroll
    for (int i = 0; i < 4; ++i) {
      int chunk = tid + 256 * i;
      int r = chunk >> 3, kc = chunk & 7;
      *(shortx8*)&sA[r * LDT + kc * 8] =
          *(const shortx8*)(A + (size_t)(m0 + r) * K + kt + kc * 8);
      *(shortx8*)&sB[r * LDT + kc * 8] =
          *(const shortx8*)(Bt + (size_t)(n0 + r) * K + kt + kc * 8);
    }
    __syncthreads();
    #pragma unroll
    for (int kk = 0; kk < 64; kk += 32) {
      bf16x8 af[4], bfr[4];
      #pragma unroll
      for (int mi = 0; mi < 4; ++mi)
        af[mi] = __builtin_bit_cast(bf16x8,
            *(const shortx8*)&sA[(wm + mi*16 + fr)*LDT + kk + quad*8]);
      #pragma unroll
      for (int ni = 0; ni < 4; ++ni)
        bfr[ni] = __builtin_bit_cast(bf16x8,
            *(const shortx8*)&sB[(wn + ni*16 + fr)*LDT + kk + quad*8]);
      #pragma unroll
      for (int mi = 0; mi < 4; ++mi)
        #pragma unroll
        for (int ni = 0; ni < 4; ++ni)
          acc[mi][ni] = __builtin_amdgcn_mfma_f32_16x16x32_bf16(
              af[mi], bfr[ni], acc[mi][ni], 0, 0, 0);
    }
    __syncthreads();
  }
  #pragma unroll
  for (int mi = 0; mi < 4; ++mi) {
    #pragma unroll
    for (int ni = 0; ni < 4; ++ni) {
      #pragma unroll
      for (int r = 0; r < 4; ++r) {
        int grow = m0 + wm + mi*16 + quad*4 + r;
        int gcol = n0 + wn + ni*16 + fr;
        float v = fmaxf(acc[mi][ni][r], 0.f);
        if constexpr (OUT_BF16)
          ((unsigned short*)Cout)[(size_t)grow * NOUT + gcol] = f2bf(v);
        else
          ((float*)Cout)[(size_t)grow * NOUT + gcol] = v;
      }
    }
  }
}

extern "C" void kernel_launch(void* const* d_in, const int* in_sizes, int n_in,
                              void* d_out, int out_size, void* d_ws, size_t ws_size,
                              hipStream_t stream) {
  (void)in_sizes; (void)n_in; (void)out_size; (void)ws_size;
  const float* xyzt = (const float*)d_in[0];
  const float* xyzs = (const float*)d_in[1];
  const float* ft   = (const float*)d_in[2];
  const float* fs   = (const float*)d_in[3];
  const float* w1   = (const float*)d_in[4];
  const float* w2   = (const float*)d_in[5];

  char* p = (char*)d_ws;
  unsigned short* w1t = (unsigned short*)p; p += (size_t)KC1*NOUT*2;
  unsigned short* w2t = (unsigned short*)p; p += (size_t)NOUT*NOUT*2;
  int*   idxb = (int*)p;   p += (size_t)MTOT*3*4;
  float* wgtb = (float*)p; p += (size_t)MTOT*3*4;
  unsigned short* Xb = (unsigned short*)p; p += (size_t)MTOT*KC1*2;
  unsigned short* Y1 = (unsigned short*)p; p += (size_t)MTOT*NOUT*2;

  // bucket/sort scratch lives inside Xb's region (consumed before build_x writes it)
  char* q = (char*)Xb;
  float4* bsrc = (float4*)q;              q += (size_t)BS*NS*16;       // 256 KB
  float4* stgt = (float4*)q;              q += (size_t)BS*NT*16;       // 1 MB
  int*    soff = (int*)q;                                              // 8.2 KB

  hipLaunchKernelGGL(wt_kernel, dim3(384), dim3(256), 0, stream, w1, w2, w1t, w2t);
  hipLaunchKernelGGL(bucket_src, dim3(BS), dim3(512), 0, stream, xyzs, bsrc, soff);
  hipLaunchKernelGGL(sort_tgt, dim3(BS), dim3(1024), 0, stream, xyzt, stgt);
  hipLaunchKernelGGL(nn_kernel, dim3(512), dim3(256), 0, stream, stgt, bsrc, soff, idxb, wgtb);
  hipLaunchKernelGGL(build_x, dim3(MTOT/4), dim3(256), 0, stream, ft, fs, idxb, wgtb, Xb);
  hipLaunchKernelGGL((mlp_gemm<KC1, true>),  dim3(MTOT/128, 2), dim3(256), 0, stream, Xb, w1t, (void*)Y1);
  hipLaunchKernelGGL((mlp_gemm<NOUT, false>), dim3(MTOT/128, 2), dim3(256), 0, stream, Y1, w2t, d_out);
}

// Round 6
// 211.507 us; speedup vs baseline: 1.6399x; 1.0796x over previous
//
#include <hip/hip_runtime.h>
#include <hip/hip_bf16.h>
#include <stdint.h>

#define BS 4
#define NS 4096
#define NT 16384
#define CS 256
#define CT 128
#define NOUT 256
#define MTOT (BS*NT) // 65536
#define GR 8
#define NC (GR*GR*GR)
#define HCELL 0.125f

typedef __attribute__((ext_vector_type(4))) float floatx4;
typedef __attribute__((ext_vector_type(8))) short shortx8;
typedef __attribute__((ext_vector_type(8))) unsigned short ushortx8;
typedef __attribute__((ext_vector_type(8))) __bf16 bf16x8;

__device__ __forceinline__ unsigned short f2bf(float f) {
  unsigned int u = __builtin_bit_cast(unsigned int, f);
  u += 0x7FFFu + ((u >> 16) & 1u);
  return (unsigned short)(u >> 16);
}
__device__ __forceinline__ float bf2f(unsigned short u) {
  return __builtin_bit_cast(float, ((unsigned int)u) << 16);
}
__device__ __forceinline__ int cell_of(float x) {
  int c = (int)(x * 8.0f);
  return min(7, max(0, c));
}

// ---------------- weight transpose + bf16 cast ----------------
__global__ __launch_bounds__(256) void wt_kernel(const float* __restrict__ w1,
    const float* __restrict__ w2, unsigned short* __restrict__ w1at,
    unsigned short* __restrict__ w1bt, unsigned short* __restrict__ w2t) {
  int i = blockIdx.x * 256 + threadIdx.x;
  {
    int n = i >> 8, k = i & 255;
    w1at[i] = f2bf(w1[k * NOUT + n]);
    w2t[i]  = f2bf(w2[k * NOUT + n]);
  }
  if (i < 256 * 128) {
    int n = i >> 7, k = i & 127;
    w1bt[i] = f2bf(w1[(256 + k) * NOUT + n]);
  }
}

// ---------------- bucket sources: counting sort by cell ----------------
__global__ __launch_bounds__(512) void bucket_src(const float* __restrict__ xyzs,
    float4* __restrict__ bsrc, int* __restrict__ soff) {
  __shared__ int cnt[NC];
  __shared__ int scan[NC];
  int tid = threadIdx.x;
  int b = blockIdx.x;
  const float* src = xyzs + (size_t)b * NS * 3;
  cnt[tid] = 0;
  __syncthreads();
  #pragma unroll
  for (int k = 0; k < 8; ++k) {
    int p = k * 512 + tid;
    float x = src[3*p], y = src[3*p+1], z = src[3*p+2];
    int c = (cell_of(z) * GR + cell_of(y)) * GR + cell_of(x);
    atomicAdd(&cnt[c], 1);
  }
  __syncthreads();
  scan[tid] = cnt[tid];
  __syncthreads();
  for (int off = 1; off < NC; off <<= 1) {
    int v = (tid >= off) ? scan[tid - off] : 0;
    __syncthreads();
    scan[tid] += v;
    __syncthreads();
  }
  int excl = scan[tid] - cnt[tid];
  cnt[tid] = excl;
  soff[b * (NC + 1) + tid] = excl;
  if (tid == 0) soff[b * (NC + 1) + NC] = NS;
  __syncthreads();
  #pragma unroll
  for (int k = 0; k < 8; ++k) {
    int p = k * 512 + tid;
    float x = src[3*p], y = src[3*p+1], z = src[3*p+2];
    int c = (cell_of(z) * GR + cell_of(y)) * GR + cell_of(x);
    int slot = atomicAdd(&cnt[c], 1);
    bsrc[(size_t)b * NS + slot] = make_float4(x, y, z, __int_as_float(p));
  }
}

// ---------------- sort targets by cell ----------------
__global__ __launch_bounds__(1024) void sort_tgt(const float* __restrict__ xyzt,
    float4* __restrict__ stgt) {
  __shared__ int cnt[NC];
  __shared__ int scan[NC];
  int tid = threadIdx.x;
  int b = blockIdx.x;
  const float* tp = xyzt + (size_t)b * NT * 3;
  if (tid < NC) cnt[tid] = 0;
  __syncthreads();
  #pragma unroll
  for (int k = 0; k < 16; ++k) {
    int p = k * 1024 + tid;
    float x = tp[3*p], y = tp[3*p+1], z = tp[3*p+2];
    int c = (cell_of(z) * GR + cell_of(y)) * GR + cell_of(x);
    atomicAdd(&cnt[c], 1);
  }
  __syncthreads();
  if (tid < NC) scan[tid] = cnt[tid];
  __syncthreads();
  for (int off = 1; off < NC; off <<= 1) {
    int v = (tid < NC && tid >= off) ? scan[tid - off] : 0;
    __syncthreads();
    if (tid < NC) scan[tid] += v;
    __syncthreads();
  }
  if (tid < NC) cnt[tid] = scan[tid] - cnt[tid];
  __syncthreads();
  #pragma unroll
  for (int k = 0; k < 16; ++k) {
    int p = k * 1024 + tid;
    float x = tp[3*p], y = tp[3*p+1], z = tp[3*p+2];
    int c = (cell_of(z) * GR + cell_of(y)) * GR + cell_of(x);
    int slot = atomicAdd(&cnt[c], 1);
    stgt[(size_t)b * NT + slot] = make_float4(x, y, z, __int_as_float(p));
  }
}

// ---------------- three_nn (bucketed, exact with clearance guard) ----------------
__device__ __forceinline__ void ins3(float sc, int jj,
    float& d0, float& d1, float& d2, int& i0, int& i1, int& i2) {
  bool l0 = sc < d0, l1 = sc < d1, l2 = sc < d2;
  d2 = l1 ? d1 : (l2 ? sc : d2);
  i2 = l1 ? i1 : (l2 ? jj : i2);
  d1 = l0 ? d0 : (l1 ? sc : d1);
  i1 = l0 ? i0 : (l1 ? jj : i1);
  d0 = l0 ? sc : d0;
  i0 = l0 ? jj : i0;
}

__device__ __forceinline__ void pair_merge(float& d0, float& d1, float& d2,
                                           int& i0, int& i1, int& i2,
                                           int delta, int sub) {
  float e0 = __shfl_xor(d0, delta);
  float e1 = __shfl_xor(d1, delta);
  float e2 = __shfl_xor(d2, delta);
  int   y0 = __shfl_xor(i0, delta);
  int   y1 = __shfl_xor(i1, delta);
  int   y2 = __shfl_xor(i2, delta);
  float a0,a1,a2,b0,b1,b2; int x0,x1,x2,z0,z1,z2;
  if ((sub & delta) == 0) { a0=d0;a1=d1;a2=d2; x0=i0;x1=i1;x2=i2;
                            b0=e0;b1=e1;b2=e2; z0=y0;z1=y1;z2=y2; }
  else                    { a0=e0;a1=e1;a2=e2; x0=y0;x1=y1;x2=y2;
                            b0=d0;b1=d1;b2=d2; z0=i0;z1=i1;z2=i2; }
  bool t = a0 <= b0;
  d0 = t ? a0 : b0; i0 = t ? x0 : z0;
  float na0 = t ? a1 : a0; int nx0 = t ? x1 : x0;
  float na1 = t ? a2 : a1; int nx1 = t ? x2 : x1;
  float nb0 = t ? b0 : b1; int nz0 = t ? z0 : z1;
  float nb1 = t ? b1 : b2; int nz1 = t ? z1 : z2;
  t = na0 <= nb0;
  d1 = t ? na0 : nb0; i1 = t ? nx0 : nz0;
  float ma0 = t ? na1 : na0; int mx0 = t ? nx1 : nx0;
  float mb0 = t ? nb0 : nb1; int mz0 = t ? nz0 : nz1;
  t = ma0 <= mb0;
  d2 = t ? ma0 : mb0; i2 = t ? mx0 : mz0;
}

__global__ __launch_bounds__(256) void nn_kernel(const float4* __restrict__ stgt,
    const float4* __restrict__ bsrc, const int* __restrict__ soff,
    int* __restrict__ idx_out, float* __restrict__ w_out) {
  __shared__ float4 s_src[NS];
  __shared__ int s_off[NC + 1];
  int tid = threadIdx.x;
  int b = blockIdx.x >> 7;
  int tseg = blockIdx.x & 127;
  for (int i = tid; i < NS; i += 256) s_src[i] = bsrc[(size_t)b * NS + i];
  for (int i = tid; i < NC + 1; i += 256) s_off[i] = soff[b * (NC + 1) + i];
  __syncthreads();
  int tpair = tid >> 1, half = tid & 1;
  float4 tg = stgt[(size_t)b * NT + tseg * 128 + tpair];
  float tx = tg.x, ty = tg.y, tz = tg.z;
  int orig = __float_as_int(tg.w);
  int cx = cell_of(tx), cy = cell_of(ty), cz = cell_of(tz);
  int wx = min(max(cx, 1), 6) - 1;
  int wy = min(max(cy, 1), 6) - 1;
  int wz = min(max(cz, 1), 6) - 1;
  float d0 = 1e30f, d1 = 1e30f, d2 = 1e30f;
  int i0 = 0, i1 = 0, i2 = 0;
  for (int r = half; r < 9; r += 2) {
    int ez = wz + r / 3, ey = wy + r % 3;
    int rowc = (ez * GR + ey) * GR + wx;
    int lo = s_off[rowc], hi = s_off[rowc + 3];
    for (int p = lo; p < hi; ++p) {
      float4 s = s_src[p];
      float dx = tx - s.x, dy = ty - s.y, dz = tz - s.z;
      float q = dx*dx + dy*dy + dz*dz;
      ins3(q, __float_as_int(s.w), d0, d1, d2, i0, i1, i2);
    }
  }
  pair_merge(d0, d1, d2, i0, i1, i2, 1, half);
  float clx = fminf(wx > 0 ? tx - wx * HCELL : 1e30f,
                    wx + 3 < GR ? (wx + 3) * HCELL - tx : 1e30f);
  float cly = fminf(wy > 0 ? ty - wy * HCELL : 1e30f,
                    wy + 3 < GR ? (wy + 3) * HCELL - ty : 1e30f);
  float clz = fminf(wz > 0 ? tz - wz * HCELL : 1e30f,
                    wz + 3 < GR ? (wz + 3) * HCELL - tz : 1e30f);
  float cl = fminf(clx, fminf(cly, clz));
  bool bad = d2 > cl * cl;
  if (__any(bad)) {
    if (bad) {
      d0 = d1 = d2 = 1e30f; i0 = i1 = i2 = 0;
      for (int p = half; p < NS; p += 2) {
        float4 s = s_src[p];
        float dx = tx - s.x, dy = ty - s.y, dz = tz - s.z;
        float q = dx*dx + dy*dy + dz*dz;
        ins3(q, __float_as_int(s.w), d0, d1, d2, i0, i1, i2);
      }
    }
    pair_merge(d0, d1, d2, i0, i1, i2, 1, half);
  }
  if (half == 0) {
    float r0 = fmaxf(sqrtf(d0), 1e-10f);
    float r1 = fmaxf(sqrtf(d1), 1e-10f);
    float r2 = fmaxf(sqrtf(d2), 1e-10f);
    float v0 = 1.f/r0, v1 = 1.f/r1, v2 = 1.f/r2;
    float sc = 1.f / ((v0 + v1 + v2) * (1.f + 1e-6f));
    size_t o = ((size_t)b * NT + orig) * 3;
    idx_out[o] = i0; idx_out[o+1] = i1; idx_out[o+2] = i2;
    w_out[o] = v0*sc; w_out[o+1] = v1*sc; w_out[o+2] = v2*sc;
  }
}

// ---------------- G = fs @ W1a  (bf16 out, no relu) ----------------
__global__ __launch_bounds__(256) void gemm_g(const float* __restrict__ fs,
    const unsigned short* __restrict__ w1at, unsigned short* __restrict__ G) {
  constexpr int LDT = 72;
  __shared__ __attribute__((aligned(16))) unsigned short sA[128 * LDT];
  __shared__ __attribute__((aligned(16))) unsigned short sB[128 * LDT];
  int tid = threadIdx.x;
  int m0 = blockIdx.x * 128;
  int n0 = blockIdx.y * 128;
  int wave = tid >> 6, lane = tid & 63;
  int wm = (wave >> 1) * 64, wn = (wave & 1) * 64;
  int fr = lane & 15, quad = lane >> 4;
  floatx4 zero = {0.f, 0.f, 0.f, 0.f};
  floatx4 acc[4][4];
  #pragma unroll
  for (int i = 0; i < 4; ++i)
    #pragma unroll
    for (int j = 0; j < 4; ++j) acc[i][j] = zero;

  for (int kt = 0; kt < 256; kt += 64) {
    // A: 128x64 fp32 -> bf16 (1024 units of 8 elems, 4/thread)  [bugfix: was i<2]
    #pragma unroll
    for (int i = 0; i < 4; ++i) {
      int u = tid + 256 * i;
      int r = u >> 3, k8 = (u & 7) * 8;
      const float* src = fs + (size_t)(m0 + r) * 256 + kt + k8;
      float4 f0 = *(const float4*)src;
      float4 f1 = *(const float4*)(src + 4);
      ushortx8 o;
      o[0]=f2bf(f0.x); o[1]=f2bf(f0.y); o[2]=f2bf(f0.z); o[3]=f2bf(f0.w);
      o[4]=f2bf(f1.x); o[5]=f2bf(f1.y); o[6]=f2bf(f1.z); o[7]=f2bf(f1.w);
      *(ushortx8*)&sA[r * LDT + k8] = o;
    }
    // B: 128x64 bf16 (1024 units of 8, 4/thread)
    #pragma unroll
    for (int i = 0; i < 4; ++i) {
      int u = tid + 256 * i;
      int n = u >> 3, kc = (u & 7) * 8;
      *(ushortx8*)&sB[n * LDT + kc] =
          *(const ushortx8*)(w1at + (size_t)(n0 + n) * 256 + kt + kc);
    }
    __syncthreads();
    #pragma unroll
    for (int kk = 0; kk < 64; kk += 32) {
      bf16x8 af[4], bfr[4];
      #pragma unroll
      for (int mi = 0; mi < 4; ++mi)
        af[mi] = __builtin_bit_cast(bf16x8,
            *(const ushortx8*)&sA[(wm + mi*16 + fr)*LDT + kk + quad*8]);
      #pragma unroll
      for (int ni = 0; ni < 4; ++ni)
        bfr[ni] = __builtin_bit_cast(bf16x8,
            *(const ushortx8*)&sB[(wn + ni*16 + fr)*LDT + kk + quad*8]);
      #pragma unroll
      for (int mi = 0; mi < 4; ++mi)
        #pragma unroll
        for (int ni = 0; ni < 4; ++ni)
          acc[mi][ni] = __builtin_amdgcn_mfma_f32_16x16x32_bf16(
              af[mi], bfr[ni], acc[mi][ni], 0, 0, 0);
    }
    __syncthreads();
  }
  #pragma unroll
  for (int mi = 0; mi < 4; ++mi)
    #pragma unroll
    for (int ni = 0; ni < 4; ++ni)
      #pragma unroll
      for (int r = 0; r < 4; ++r) {
        int grow = m0 + wm + mi*16 + quad*4 + r;
        int gcol = n0 + wn + ni*16 + fr;
        G[(size_t)grow * 256 + gcol] = f2bf(acc[mi][ni][r]);
      }
}

// ---------------- fused: out = relu(relu(interp + ft@W1b) @ W2) ----------------
__global__ __launch_bounds__(256) void fused_mlp(const float* __restrict__ ft,
    const unsigned short* __restrict__ G, const int* __restrict__ idxb,
    const float* __restrict__ wgtb, const unsigned short* __restrict__ w1bt,
    const unsigned short* __restrict__ w2t, float* __restrict__ out) {
  constexpr int LDI = 264;
  constexpr int LDT = 72;
  __shared__ __attribute__((aligned(16))) unsigned short sI[64 * LDI];
  __shared__ __attribute__((aligned(16))) unsigned short sA[64 * LDT];
  __shared__ __attribute__((aligned(16))) unsigned short sB[256 * LDT];
  int tid = threadIdx.x;
  int row0 = blockIdx.x * 64;
  int b = row0 >> 14;
  int wave = tid >> 6, lane = tid & 63;
  int wn = wave * 64;
  int fr = lane & 15, quad = lane >> 4;

  // ---- build interp tile into sI (bf16)
  {
    int r = tid >> 2, seg = tid & 3;
    int grow = row0 + r;
    const int* ip = idxb + (size_t)grow * 3;
    const float* wp = wgtb + (size_t)grow * 3;
    int g0i = ip[0], g1i = ip[1], g2i = ip[2];
    float w0 = wp[0], w1v = wp[1], w2v = wp[2];
    const unsigned short* Gb = G + ((size_t)b << 20);
    const unsigned short* g0 = Gb + ((size_t)g0i << 8) + seg * 64;
    const unsigned short* g1 = Gb + ((size_t)g1i << 8) + seg * 64;
    const unsigned short* g2 = Gb + ((size_t)g2i << 8) + seg * 64;
    #pragma unroll
    for (int j = 0; j < 8; ++j) {
      ushortx8 a = *(const ushortx8*)(g0 + j*8);
      ushortx8 c = *(const ushortx8*)(g1 + j*8);
      ushortx8 e = *(const ushortx8*)(g2 + j*8);
      ushortx8 o;
      #pragma unroll
      for (int q = 0; q < 8; ++q)
        o[q] = f2bf(w0*bf2f(a[q]) + w1v*bf2f(c[q]) + w2v*bf2f(e[q]));
      *(ushortx8*)&sI[r * LDI + seg * 64 + j * 8] = o;
    }
  }

  floatx4 zero = {0.f, 0.f, 0.f, 0.f};
  floatx4 acc[4][4];
  #pragma unroll
  for (int i = 0; i < 4; ++i)
    #pragma unroll
    for (int j = 0; j < 4; ++j) acc[i][j] = zero;

  // ---- phase 1: ft @ W1b  (K=128)
  for (int kt = 0; kt < 128; kt += 64) {
    #pragma unroll
    for (int i = 0; i < 2; ++i) {
      int u = tid + 256 * i;
      int r = u >> 3, k8 = (u & 7) * 8;
      const float* src = ft + (size_t)(row0 + r) * CT + kt + k8;
      float4 f0 = *(const float4*)src;
      float4 f1 = *(const float4*)(src + 4);
      ushortx8 o;
      o[0]=f2bf(f0.x); o[1]=f2bf(f0.y); o[2]=f2bf(f0.z); o[3]=f2bf(f0.w);
      o[4]=f2bf(f1.x); o[5]=f2bf(f1.y); o[6]=f2bf(f1.z); o[7]=f2bf(f1.w);
      *(ushortx8*)&sA[r * LDT + k8] = o;
    }
    #pragma unroll
    for (int i = 0; i < 8; ++i) {
      int u = tid + 256 * i;
      int n = u >> 3, kc = (u & 7) * 8;
      *(ushortx8*)&sB[n * LDT + kc] =
          *(const ushortx8*)(w1bt + (size_t)n * CT + kt + kc);
    }
    __syncthreads();
    #pragma unroll
    for (int kk = 0; kk < 64; kk += 32) {
      bf16x8 af[4], bfr[4];
      #pragma unroll
      for (int mi = 0; mi < 4; ++mi)
        af[mi] = __builtin_bit_cast(bf16x8,
            *(const ushortx8*)&sA[(mi*16 + fr)*LDT + kk + quad*8]);
      #pragma unroll
      for (int ni = 0; ni < 4; ++ni)
        bfr[ni] = __builtin_bit_cast(bf16x8,
            *(const ushortx8*)&sB[(wn + ni*16 + fr)*LDT + kk + quad*8]);
      #pragma unroll
      for (int mi = 0; mi < 4; ++mi)
        #pragma unroll
        for (int ni = 0; ni < 4; ++ni)
          acc[mi][ni] = __builtin_amdgcn_mfma_f32_16x16x32_bf16(
              af[mi], bfr[ni], acc[mi][ni], 0, 0, 0);
    }
    __syncthreads();
  }

  // ---- phase-1 epilogue: T = relu(acc + interp), bf16 in-place in sI
  #pragma unroll
  for (int mi = 0; mi < 4; ++mi)
    #pragma unroll
    for (int ni = 0; ni < 4; ++ni)
      #pragma unroll
      for (int r = 0; r < 4; ++r) {
        int lr = mi*16 + quad*4 + r;
        int lc = wn + ni*16 + fr;
        float v = acc[mi][ni][r] + bf2f(sI[lr * LDI + lc]);
        sI[lr * LDI + lc] = f2bf(fmaxf(v, 0.f));
      }
  __syncthreads();

  // ---- phase 2: T @ W2 (K=256)
  #pragma unroll
  for (int i = 0; i < 4; ++i)
    #pragma unroll
    for (int j = 0; j < 4; ++j) acc[i][j] = zero;
  for (int kt = 0; kt < 256; kt += 64) {
    #pragma unroll
    for (int i = 0; i < 8; ++i) {
      int u = tid + 256 * i;
      int n = u >> 3, kc = (u & 7) * 8;
      *(ushortx8*)&sB[n * LDT + kc] =
          *(const ushortx8*)(w2t + (size_t)n * 256 + kt + kc);
    }
    __syncthreads();
    #pragma unroll
    for (int kk = 0; kk < 64; kk += 32) {
      bf16x8 af[4], bfr[4];
      #pragma unroll
      for (int mi = 0; mi < 4; ++mi)
        af[mi] = __builtin_bit_cast(bf16x8,
            *(const ushortx8*)&sI[(mi*16 + fr)*LDI + kt + kk + quad*8]);
      #pragma unroll
      for (int ni = 0; ni < 4; ++ni)
        bfr[ni] = __builtin_bit_cast(bf16x8,
            *(const ushortx8*)&sB[(wn + ni*16 + fr)*LDT + kk + quad*8]);
      #pragma unroll
      for (int mi = 0; mi < 4; ++mi)
        #pragma unroll
        for (int ni = 0; ni < 4; ++ni)
          acc[mi][ni] = __builtin_amdgcn_mfma_f32_16x16x32_bf16(
              af[mi], bfr[ni], acc[mi][ni], 0, 0, 0);
    }
    __syncthreads();
  }
  #pragma unroll
  for (int mi = 0; mi < 4; ++mi)
    #pragma unroll
    for (int ni = 0; ni < 4; ++ni)
      #pragma unroll
      for (int r = 0; r < 4; ++r) {
        int grow = row0 + mi*16 + quad*4 + r;
        int gcol = wn + ni*16 + fr;
        out[(size_t)grow * 256 + gcol] = fmaxf(acc[mi][ni][r], 0.f);
      }
}

extern "C" void kernel_launch(void* const* d_in, const int* in_sizes, int n_in,
                              void* d_out, int out_size, void* d_ws, size_t ws_size,
                              hipStream_t stream) {
  (void)in_sizes; (void)n_in; (void)out_size; (void)ws_size;
  const float* xyzt = (const float*)d_in[0];
  const float* xyzs = (const float*)d_in[1];
  const float* ft   = (const float*)d_in[2];
  const float* fs   = (const float*)d_in[3];
  const float* w1   = (const float*)d_in[4];
  const float* w2   = (const float*)d_in[5];

  char* p = (char*)d_ws;
  unsigned short* w1at = (unsigned short*)p; p += (size_t)256*256*2;
  unsigned short* w1bt = (unsigned short*)p; p += (size_t)256*128*2;
  unsigned short* w2t  = (unsigned short*)p; p += (size_t)256*256*2;
  int*   idxb = (int*)p;   p += (size_t)MTOT*3*4;
  float* wgtb = (float*)p; p += (size_t)MTOT*3*4;
  unsigned short* G = (unsigned short*)p; p += (size_t)BS*NS*NOUT*2;
  float4* bsrc = (float4*)p; p += (size_t)BS*NS*16;
  float4* stgt = (float4*)p; p += (size_t)BS*NT*16;
  int*    soff = (int*)p;

  hipLaunchKernelGGL(wt_kernel, dim3(256), dim3(256), 0, stream, w1, w2, w1at, w1bt, w2t);
  hipLaunchKernelGGL(bucket_src, dim3(BS), dim3(512), 0, stream, xyzs, bsrc, soff);
  hipLaunchKernelGGL(sort_tgt, dim3(BS), dim3(1024), 0, stream, xyzt, stgt);
  hipLaunchKernelGGL(nn_kernel, dim3(512), dim3(256), 0, stream, stgt, bsrc, soff, idxb, wgtb);
  hipLaunchKernelGGL(gemm_g, dim3(BS*NS/128, 2), dim3(256), 0, stream, fs, w1at, G);
  hipLaunchKernelGGL(fused_mlp, dim3(MTOT/64), dim3(256), 0, stream,
                     ft, G, idxb, wgtb, w1bt, w2t, (float*)d_out);
}

// Round 7
// 196.169 us; speedup vs baseline: 1.7681x; 1.0782x over previous
//
#include <hip/hip_runtime.h>
#include <hip/hip_bf16.h>
#include <stdint.h>

#define BS 4
#define NS 4096
#define NT 16384
#define CT 128
#define NOUT 256
#define MTOT (BS*NT) // 65536
#define GR 8
#define NC (GR*GR*GR)
#define HCELL 0.125f

typedef __attribute__((ext_vector_type(4))) float floatx4;
typedef __attribute__((ext_vector_type(8))) unsigned short ushortx8;
typedef __attribute__((ext_vector_type(8))) __bf16 bf16x8;

__device__ __forceinline__ unsigned short f2bf(float f) {
  unsigned int u = __builtin_bit_cast(unsigned int, f);
  u += 0x7FFFu + ((u >> 16) & 1u);
  return (unsigned short)(u >> 16);
}
__device__ __forceinline__ float bf2f(unsigned short u) {
  return __builtin_bit_cast(float, ((unsigned int)u) << 16);
}
__device__ __forceinline__ int cell_of(float x) {
  int c = (int)(x * 8.0f);
  return min(7, max(0, c));
}

// ---------------- prep: bucket sources (blk 0-3) + sort targets (blk 4-7) + weight transpose (blk 8+) ----------------
__global__ __launch_bounds__(1024) void prep_kernel(
    const float* __restrict__ xyzs, const float* __restrict__ xyzt,
    const float* __restrict__ w1, const float* __restrict__ w2,
    float4* __restrict__ bsrc, int* __restrict__ soff, float4* __restrict__ stgt,
    unsigned short* __restrict__ w1at, unsigned short* __restrict__ w1bt,
    unsigned short* __restrict__ w2t) {
  int bid = blockIdx.x, tid = threadIdx.x;
  if (bid < 8) {
    __shared__ int cnt[NC];
    __shared__ int scan[NC];
    int b = bid & 3;
    bool isrc = bid < 4;
    int per = isrc ? (NS >> 10) : (NT >> 10);
    const float* in = isrc ? xyzs + (size_t)b * NS * 3 : xyzt + (size_t)b * NT * 3;
    float4* outp = isrc ? bsrc + (size_t)b * NS : stgt + (size_t)b * NT;
    if (tid < NC) cnt[tid] = 0;
    __syncthreads();
    for (int k = 0; k < per; ++k) {
      int p = k * 1024 + tid;
      float x = in[3*p], y = in[3*p+1], z = in[3*p+2];
      int c = (cell_of(z) * GR + cell_of(y)) * GR + cell_of(x);
      atomicAdd(&cnt[c], 1);
    }
    __syncthreads();
    if (tid < NC) scan[tid] = cnt[tid];
    __syncthreads();
    for (int off = 1; off < NC; off <<= 1) {
      int v = (tid < NC && tid >= off) ? scan[tid - off] : 0;
      __syncthreads();
      if (tid < NC) scan[tid] += v;
      __syncthreads();
    }
    if (tid < NC) {
      int excl = scan[tid] - cnt[tid];
      cnt[tid] = excl;
      if (isrc) soff[b * (NC + 1) + tid] = excl;
    }
    if (isrc && tid == 0) soff[b * (NC + 1) + NC] = NS;
    __syncthreads();
    for (int k = 0; k < per; ++k) {
      int p = k * 1024 + tid;
      float x = in[3*p], y = in[3*p+1], z = in[3*p+2];
      int c = (cell_of(z) * GR + cell_of(y)) * GR + cell_of(x);
      int slot = atomicAdd(&cnt[c], 1);
      outp[slot] = make_float4(x, y, z, __int_as_float(p));
    }
  } else {
    int i = (bid - 8) * 1024 + tid;  // i < 65536
    int n = i >> 8, k = i & 255;
    w1at[i] = f2bf(w1[k * NOUT + n]);
    w2t[i]  = f2bf(w2[k * NOUT + n]);
    if (i < 256 * 128) {
      int n2 = i >> 7, k2 = i & 127;
      w1bt[i] = f2bf(w1[(256 + k2) * NOUT + n2]);
    }
  }
}

// ---------------- three_nn (bucketed, exact w/ clearance guard); outputs at SORTED positions ----------------
__device__ __forceinline__ void ins3(float sc, int jj,
    float& d0, float& d1, float& d2, int& i0, int& i1, int& i2) {
  bool l0 = sc < d0, l1 = sc < d1, l2 = sc < d2;
  d2 = l1 ? d1 : (l2 ? sc : d2);
  i2 = l1 ? i1 : (l2 ? jj : i2);
  d1 = l0 ? d0 : (l1 ? sc : d1);
  i1 = l0 ? i0 : (l1 ? jj : i1);
  d0 = l0 ? sc : d0;
  i0 = l0 ? jj : i0;
}

__device__ __forceinline__ void pair_merge(float& d0, float& d1, float& d2,
                                           int& i0, int& i1, int& i2,
                                           int delta, int sub) {
  float e0 = __shfl_xor(d0, delta);
  float e1 = __shfl_xor(d1, delta);
  float e2 = __shfl_xor(d2, delta);
  int   y0 = __shfl_xor(i0, delta);
  int   y1 = __shfl_xor(i1, delta);
  int   y2 = __shfl_xor(i2, delta);
  float a0,a1,a2,b0,b1,b2; int x0,x1,x2,z0,z1,z2;
  if ((sub & delta) == 0) { a0=d0;a1=d1;a2=d2; x0=i0;x1=i1;x2=i2;
                            b0=e0;b1=e1;b2=e2; z0=y0;z1=y1;z2=y2; }
  else                    { a0=e0;a1=e1;a2=e2; x0=y0;x1=y1;x2=y2;
                            b0=d0;b1=d1;b2=d2; z0=i0;z1=i1;z2=i2; }
  bool t = a0 <= b0;
  d0 = t ? a0 : b0; i0 = t ? x0 : z0;
  float na0 = t ? a1 : a0; int nx0 = t ? x1 : x0;
  float na1 = t ? a2 : a1; int nx1 = t ? x2 : x1;
  float nb0 = t ? b0 : b1; int nz0 = t ? z0 : z1;
  float nb1 = t ? b1 : b2; int nz1 = t ? z1 : z2;
  t = na0 <= nb0;
  d1 = t ? na0 : nb0; i1 = t ? nx0 : nz0;
  float ma0 = t ? na1 : na0; int mx0 = t ? nx1 : nx0;
  float mb0 = t ? nb0 : nb1; int mz0 = t ? nz0 : nz1;
  t = ma0 <= mb0;
  d2 = t ? ma0 : mb0; i2 = t ? mx0 : mz0;
}

__global__ __launch_bounds__(256) void nn_kernel(const float4* __restrict__ stgt,
    const float4* __restrict__ bsrc, const int* __restrict__ soff,
    int* __restrict__ idx_out, float* __restrict__ w_out) {
  __shared__ float4 s_src[NS];
  __shared__ int s_off[NC + 1];
  int tid = threadIdx.x;
  int b = blockIdx.x >> 7;
  int tseg = blockIdx.x & 127;
  for (int i = tid; i < NS; i += 256) s_src[i] = bsrc[(size_t)b * NS + i];
  for (int i = tid; i < NC + 1; i += 256) s_off[i] = soff[b * (NC + 1) + i];
  __syncthreads();
  int tpair = tid >> 1, half = tid & 1;
  float4 tg = stgt[(size_t)b * NT + tseg * 128 + tpair];
  float tx = tg.x, ty = tg.y, tz = tg.z;
  int cx = cell_of(tx), cy = cell_of(ty), cz = cell_of(tz);
  int wx = min(max(cx, 1), 6) - 1;
  int wy = min(max(cy, 1), 6) - 1;
  int wz = min(max(cz, 1), 6) - 1;
  float d0 = 1e30f, d1 = 1e30f, d2 = 1e30f;
  int i0 = 0, i1 = 0, i2 = 0;
  for (int r = half; r < 9; r += 2) {
    int ez = wz + r / 3, ey = wy + r % 3;
    int rowc = (ez * GR + ey) * GR + wx;
    int lo = s_off[rowc], hi = s_off[rowc + 3];
    for (int p = lo; p < hi; ++p) {
      float4 s = s_src[p];
      float dx = tx - s.x, dy = ty - s.y, dz = tz - s.z;
      float q = dx*dx + dy*dy + dz*dz;
      ins3(q, __float_as_int(s.w), d0, d1, d2, i0, i1, i2);
    }
  }
  pair_merge(d0, d1, d2, i0, i1, i2, 1, half);
  float clx = fminf(wx > 0 ? tx - wx * HCELL : 1e30f,
                    wx + 3 < GR ? (wx + 3) * HCELL - tx : 1e30f);
  float cly = fminf(wy > 0 ? ty - wy * HCELL : 1e30f,
                    wy + 3 < GR ? (wy + 3) * HCELL - ty : 1e30f);
  float clz = fminf(wz > 0 ? tz - wz * HCELL : 1e30f,
                    wz + 3 < GR ? (wz + 3) * HCELL - tz : 1e30f);
  float cl = fminf(clx, fminf(cly, clz));
  bool bad = d2 > cl * cl;
  if (__any(bad)) {
    if (bad) {
      d0 = d1 = d2 = 1e30f; i0 = i1 = i2 = 0;
      for (int p = half; p < NS; p += 2) {
        float4 s = s_src[p];
        float dx = tx - s.x, dy = ty - s.y, dz = tz - s.z;
        float q = dx*dx + dy*dy + dz*dz;
        ins3(q, __float_as_int(s.w), d0, d1, d2, i0, i1, i2);
      }
    }
    pair_merge(d0, d1, d2, i0, i1, i2, 1, half);
  }
  if (half == 0) {
    float r0 = fmaxf(sqrtf(d0), 1e-10f);
    float r1 = fmaxf(sqrtf(d1), 1e-10f);
    float r2 = fmaxf(sqrtf(d2), 1e-10f);
    float v0 = 1.f/r0, v1 = 1.f/r1, v2 = 1.f/r2;
    float sc = 1.f / ((v0 + v1 + v2) * (1.f + 1e-6f));
    // write at SORTED position (fused_mlp consumes sorted order)
    size_t o = ((size_t)b * NT + tseg * 128 + tpair) * 3;
    idx_out[o] = i0; idx_out[o+1] = i1; idx_out[o+2] = i2;
    w_out[o] = v0*sc; w_out[o+1] = v1*sc; w_out[o+2] = v2*sc;
  }
}

// ---------------- G = fs @ W1a  (bf16 out, no relu) ----------------
__global__ __launch_bounds__(256) void gemm_g(const float* __restrict__ fs,
    const unsigned short* __restrict__ w1at, unsigned short* __restrict__ G) {
  constexpr int LDT = 72;
  __shared__ __attribute__((aligned(16))) unsigned short sA[128 * LDT];
  __shared__ __attribute__((aligned(16))) unsigned short sB[128 * LDT];
  int tid = threadIdx.x;
  int m0 = blockIdx.x * 128;
  int n0 = blockIdx.y * 128;
  int wave = tid >> 6, lane = tid & 63;
  int wm = (wave >> 1) * 64, wn = (wave & 1) * 64;
  int fr = lane & 15, quad = lane >> 4;
  floatx4 zero = {0.f, 0.f, 0.f, 0.f};
  floatx4 acc[4][4];
  #pragma unroll
  for (int i = 0; i < 4; ++i)
    #pragma unroll
    for (int j = 0; j < 4; ++j) acc[i][j] = zero;

  for (int kt = 0; kt < 256; kt += 64) {
    #pragma unroll
    for (int i = 0; i < 4; ++i) {
      int u = tid + 256 * i;
      int r = u >> 3, k8 = (u & 7) * 8;
      const float* src = fs + (size_t)(m0 + r) * 256 + kt + k8;
      float4 f0 = *(const float4*)src;
      float4 f1 = *(const float4*)(src + 4);
      ushortx8 o;
      o[0]=f2bf(f0.x); o[1]=f2bf(f0.y); o[2]=f2bf(f0.z); o[3]=f2bf(f0.w);
      o[4]=f2bf(f1.x); o[5]=f2bf(f1.y); o[6]=f2bf(f1.z); o[7]=f2bf(f1.w);
      *(ushortx8*)&sA[r * LDT + k8] = o;
    }
    #pragma unroll
    for (int i = 0; i < 4; ++i) {
      int u = tid + 256 * i;
      int n = u >> 3, kc = (u & 7) * 8;
      *(ushortx8*)&sB[n * LDT + kc] =
          *(const ushortx8*)(w1at + (size_t)(n0 + n) * 256 + kt + kc);
    }
    __syncthreads();
    #pragma unroll
    for (int kk = 0; kk < 64; kk += 32) {
      bf16x8 af[4], bfr[4];
      #pragma unroll
      for (int mi = 0; mi < 4; ++mi)
        af[mi] = __builtin_bit_cast(bf16x8,
            *(const ushortx8*)&sA[(wm + mi*16 + fr)*LDT + kk + quad*8]);
      #pragma unroll
      for (int ni = 0; ni < 4; ++ni)
        bfr[ni] = __builtin_bit_cast(bf16x8,
            *(const ushortx8*)&sB[(wn + ni*16 + fr)*LDT + kk + quad*8]);
      #pragma unroll
      for (int mi = 0; mi < 4; ++mi)
        #pragma unroll
        for (int ni = 0; ni < 4; ++ni)
          acc[mi][ni] = __builtin_amdgcn_mfma_f32_16x16x32_bf16(
              af[mi], bfr[ni], acc[mi][ni], 0, 0, 0);
    }
    __syncthreads();
  }
  #pragma unroll
  for (int mi = 0; mi < 4; ++mi)
    #pragma unroll
    for (int ni = 0; ni < 4; ++ni)
      #pragma unroll
      for (int r = 0; r < 4; ++r) {
        int grow = m0 + wm + mi*16 + quad*4 + r;
        int gcol = n0 + wn + ni*16 + fr;
        G[(size_t)grow * 256 + gcol] = f2bf(acc[mi][ni][r]);
      }
}

// ---------------- fused: out[orig] = relu(relu(interp + ft[orig]@W1b) @ W2) ----------------
// sorted-order rows; B-fragments loaded directly from global (weights L2-resident).
// LDS: sI 64x264 (interp->T) 33.8 KB + sF 64x136 (ft tile) 17.4 KB = 51.2 KB -> 3 blocks/CU.
__global__ __launch_bounds__(256, 3) void fused_mlp(const float* __restrict__ ft,
    const unsigned short* __restrict__ G, const int* __restrict__ idxb,
    const float* __restrict__ wgtb, const float4* __restrict__ stgt,
    const unsigned short* __restrict__ w1bt, const unsigned short* __restrict__ w2t,
    float* __restrict__ out) {
  constexpr int LDI = 264;
  constexpr int LDF = 136;
  __shared__ __attribute__((aligned(16))) unsigned short sI[64 * LDI];
  __shared__ __attribute__((aligned(16))) unsigned short sF[64 * LDF];
  int tid = threadIdx.x;
  int row0 = blockIdx.x * 64;   // global sorted row
  int b = row0 >> 14;
  const float4* st = stgt + ((size_t)b << 14) + (row0 & (NT - 1));
  const float* ftb = ft + (size_t)b * NT * CT;
  float* outb = out + (size_t)b * NT * NOUT;
  int wave = tid >> 6, lane = tid & 63;
  int wn = wave * 64;
  int fr = lane & 15, quad = lane >> 4;

  // ---- interp tile into sI (bf16); idx/wgt are at sorted positions
  {
    int r = tid >> 2, seg = tid & 3;
    const int* ip = idxb + (size_t)(row0 + r) * 3;
    const float* wp = wgtb + (size_t)(row0 + r) * 3;
    int g0i = ip[0], g1i = ip[1], g2i = ip[2];
    float w0 = wp[0], w1v = wp[1], w2v = wp[2];
    const unsigned short* Gb = G + ((size_t)b << 20);
    const unsigned short* g0 = Gb + ((size_t)g0i << 8) + seg * 64;
    const unsigned short* g1 = Gb + ((size_t)g1i << 8) + seg * 64;
    const unsigned short* g2 = Gb + ((size_t)g2i << 8) + seg * 64;
    #pragma unroll
    for (int j = 0; j < 8; ++j) {
      ushortx8 a = *(const ushortx8*)(g0 + j*8);
      ushortx8 c = *(const ushortx8*)(g1 + j*8);
      ushortx8 e = *(const ushortx8*)(g2 + j*8);
      ushortx8 o;
      #pragma unroll
      for (int q = 0; q < 8; ++q)
        o[q] = f2bf(w0*bf2f(a[q]) + w1v*bf2f(c[q]) + w2v*bf2f(e[q]));
      *(ushortx8*)&sI[r * LDI + seg * 64 + j * 8] = o;
    }
  }
  // ---- full ft tile (64x128) fp32->bf16: 1024 units of 8, 4/thread; rows gathered via orig
  #pragma unroll
  for (int i = 0; i < 4; ++i) {
    int u = tid + 256 * i;
    int r = u >> 4, k8 = (u & 15) * 8;
    int orig = __float_as_int(st[r].w);
    const float* src = ftb + (size_t)orig * CT + k8;
    float4 f0 = *(const float4*)src;
    float4 f1 = *(const float4*)(src + 4);
    ushortx8 o;
    o[0]=f2bf(f0.x); o[1]=f2bf(f0.y); o[2]=f2bf(f0.z); o[3]=f2bf(f0.w);
    o[4]=f2bf(f1.x); o[5]=f2bf(f1.y); o[6]=f2bf(f1.z); o[7]=f2bf(f1.w);
    *(ushortx8*)&sF[r * LDF + k8] = o;
  }
  __syncthreads();

  floatx4 zero = {0.f, 0.f, 0.f, 0.f};
  floatx4 acc[4][4];
  #pragma unroll
  for (int i = 0; i < 4; ++i)
    #pragma unroll
    for (int j = 0; j < 4; ++j) acc[i][j] = zero;

  // ---- phase 1: ft @ W1b (K=128), B-frags direct from global
  #pragma unroll
  for (int kk = 0; kk < 128; kk += 32) {
    bf16x8 af[4], bfr[4];
    #pragma unroll
    for (int mi = 0; mi < 4; ++mi)
      af[mi] = __builtin_bit_cast(bf16x8,
          *(const ushortx8*)&sF[(mi*16 + fr)*LDF + kk + quad*8]);
    #pragma unroll
    for (int ni = 0; ni < 4; ++ni)
      bfr[ni] = __builtin_bit_cast(bf16x8,
          *(const ushortx8*)(w1bt + (size_t)(wn + ni*16 + fr) * CT + kk + quad*8));
    #pragma unroll
    for (int mi = 0; mi < 4; ++mi)
      #pragma unroll
      for (int ni = 0; ni < 4; ++ni)
        acc[mi][ni] = __builtin_amdgcn_mfma_f32_16x16x32_bf16(
            af[mi], bfr[ni], acc[mi][ni], 0, 0, 0);
  }

  // ---- phase-1 epilogue: T = relu(acc + interp) bf16, in-place in sI (own cells)
  #pragma unroll
  for (int mi = 0; mi < 4; ++mi)
    #pragma unroll
    for (int ni = 0; ni < 4; ++ni)
      #pragma unroll
      for (int r = 0; r < 4; ++r) {
        int lr = mi*16 + quad*4 + r;
        int lc = wn + ni*16 + fr;
        float v = acc[mi][ni][r] + bf2f(sI[lr * LDI + lc]);
        sI[lr * LDI + lc] = f2bf(fmaxf(v, 0.f));
      }
  __syncthreads();

  // ---- phase 2: T @ W2 (K=256), no barriers
  #pragma unroll
  for (int i = 0; i < 4; ++i)
    #pragma unroll
    for (int j = 0; j < 4; ++j) acc[i][j] = zero;
  #pragma unroll
  for (int kk = 0; kk < 256; kk += 32) {
    bf16x8 af[4], bfr[4];
    #pragma unroll
    for (int mi = 0; mi < 4; ++mi)
      af[mi] = __builtin_bit_cast(bf16x8,
          *(const ushortx8*)&sI[(mi*16 + fr)*LDI + kk + quad*8]);
    #pragma unroll
    for (int ni = 0; ni < 4; ++ni)
      bfr[ni] = __builtin_bit_cast(bf16x8,
          *(const ushortx8*)(w2t + (size_t)(wn + ni*16 + fr) * NOUT + kk + quad*8));
    #pragma unroll
    for (int mi = 0; mi < 4; ++mi)
      #pragma unroll
      for (int ni = 0; ni < 4; ++ni)
        acc[mi][ni] = __builtin_amdgcn_mfma_f32_16x16x32_bf16(
            af[mi], bfr[ni], acc[mi][ni], 0, 0, 0);
  }
  // ---- out epilogue: scatter rows back to original positions
  #pragma unroll
  for (int mi = 0; mi < 4; ++mi)
    #pragma unroll
    for (int r = 0; r < 4; ++r) {
      int lr = mi*16 + quad*4 + r;
      int orig = __float_as_int(st[lr].w);
      float* orow = outb + (size_t)orig * NOUT;
      #pragma unroll
      for (int ni = 0; ni < 4; ++ni)
        orow[wn + ni*16 + fr] = fmaxf(acc[mi][ni][r], 0.f);
    }
}

extern "C" void kernel_launch(void* const* d_in, const int* in_sizes, int n_in,
                              void* d_out, int out_size, void* d_ws, size_t ws_size,
                              hipStream_t stream) {
  (void)in_sizes; (void)n_in; (void)out_size; (void)ws_size;
  const float* xyzt = (const float*)d_in[0];
  const float* xyzs = (const float*)d_in[1];
  const float* ft   = (const float*)d_in[2];
  const float* fs   = (const float*)d_in[3];
  const float* w1   = (const float*)d_in[4];
  const float* w2   = (const float*)d_in[5];

  char* p = (char*)d_ws;
  unsigned short* w1at = (unsigned short*)p; p += (size_t)256*256*2;
  unsigned short* w1bt = (unsigned short*)p; p += (size_t)256*128*2;
  unsigned short* w2t  = (unsigned short*)p; p += (size_t)256*256*2;
  int*   idxb = (int*)p;   p += (size_t)MTOT*3*4;
  float* wgtb = (float*)p; p += (size_t)MTOT*3*4;
  unsigned short* G = (unsigned short*)p; p += (size_t)BS*NS*NOUT*2;
  float4* bsrc = (float4*)p; p += (size_t)BS*NS*16;
  float4* stgt = (float4*)p; p += (size_t)BS*NT*16;
  int*    soff = (int*)p;

  hipLaunchKernelGGL(prep_kernel, dim3(8 + 64), dim3(1024), 0, stream,
                     xyzs, xyzt, w1, w2, bsrc, soff, stgt, w1at, w1bt, w2t);
  hipLaunchKernelGGL(nn_kernel, dim3(512), dim3(256), 0, stream, stgt, bsrc, soff, idxb, wgtb);
  hipLaunchKernelGGL(gemm_g, dim3(BS*NS/128, 2), dim3(256), 0, stream, fs, w1at, G);
  hipLaunchKernelGGL(fused_mlp, dim3(MTOT/64), dim3(256), 0, stream,
                     ft, G, idxb, wgtb, stgt, w1bt, w2t, (float*)d_out);
}